// Round 2
// baseline (153.756 us; speedup 1.0000x reference)
//
#include <hip/hip_runtime.h>

#define NTOK 256
#define LOG2E 1.44269504088896340736f
#define LN_EPS 1e-5f

// -------- Kernel A: per-token KV projections for both attentions --------
// ws layout: [batch][token] float4 (k0,k1,v0,v1) for self-attn, then the
// same block for cross-attn at offset NB*NTOK.
__global__ __launch_bounds__(256, 4)
void kv_producer_kernel(
    const float* __restrict__ x, const float* __restrict__ m,
    const float* __restrict__ sa_w_in, const float* __restrict__ sa_b_in,
    const float* __restrict__ ca_w_in, const float* __restrict__ ca_b_in,
    const float* __restrict__ ln1_g, const float* __restrict__ ln1_b,
    float4* __restrict__ ws_sa, float4* __restrict__ ws_ca)
{
    const int gid = blockIdx.x * blockDim.x + threadIdx.x;   // token id

    // self-attn K,V come from LN1(x)
    float2 hv = ((const float2*)x)[gid];
    float diff = 0.5f * (hv.x - hv.y);
    float n = diff * rsqrtf(diff * diff + LN_EPS);
    float h0 =  n * ln1_g[0] + ln1_b[0];
    float h1 = -n * ln1_g[1] + ln1_b[1];
    float4 sa;
    sa.x = h0*sa_w_in[4]  + h1*sa_w_in[5]  + sa_b_in[2];
    sa.y = h0*sa_w_in[6]  + h1*sa_w_in[7]  + sa_b_in[3];
    sa.z = h0*sa_w_in[8]  + h1*sa_w_in[9]  + sa_b_in[4];
    sa.w = h0*sa_w_in[10] + h1*sa_w_in[11] + sa_b_in[5];
    ws_sa[gid] = sa;

    // cross-attn K,V come from raw m
    float2 mv = ((const float2*)m)[gid];
    float4 ca;
    ca.x = mv.x*ca_w_in[4]  + mv.y*ca_w_in[5]  + ca_b_in[2];
    ca.y = mv.x*ca_w_in[6]  + mv.y*ca_w_in[7]  + ca_b_in[3];
    ca.z = mv.x*ca_w_in[8]  + mv.y*ca_w_in[9]  + ca_b_in[4];
    ca.w = mv.x*ca_w_in[10] + mv.y*ca_w_in[11] + ca_b_in[5];
    ws_ca[gid] = ca;
}

// -------- Kernel B: fully-fused decoder layer, KV via wave-uniform loads ----
// No LDS, no __syncthreads. KV reads have uniform addresses (blockIdx + loop
// counter) from a read-only restrict buffer -> compiler emits s_load; the
// inner-loop FMAs take the KV operand from SGPRs (1 SGPR/VALU-instr is legal).
__global__ __launch_bounds__(256, 4)
void att_decoder_kernel(
    const float* __restrict__ x,
    const float4* __restrict__ ws_sa, const float4* __restrict__ ws_ca,
    const float* __restrict__ sa_w_in, const float* __restrict__ sa_b_in,
    const float* __restrict__ sa_w_out, const float* __restrict__ sa_b_out,
    const float* __restrict__ ca_w_in, const float* __restrict__ ca_b_in,
    const float* __restrict__ ca_w_out, const float* __restrict__ ca_b_out,
    const float* __restrict__ ln1_g, const float* __restrict__ ln1_b,
    const float* __restrict__ ln2_g, const float* __restrict__ ln2_b,
    const float* __restrict__ ln3_g, const float* __restrict__ ln3_b,
    const float* __restrict__ f_w1, const float* __restrict__ f_b1,
    const float* __restrict__ f_ln_g, const float* __restrict__ f_ln_b,
    const float* __restrict__ f_w2, const float* __restrict__ f_b2,
    float* __restrict__ out)
{
    const int b = blockIdx.x;
    const int t = threadIdx.x;

    float2 hv = ((const float2*)x)[b * NTOK + t];
    float h0 = hv.x, h1 = hv.y;

    // ---- LN1 (d=2 closed form) ----
    {
        float diff = 0.5f * (h0 - h1);
        float n = diff * rsqrtf(diff * diff + LN_EPS);
        h0 =  n * ln1_g[0] + ln1_b[0];
        h1 = -n * ln1_g[1] + ln1_b[1];
    }

    const float sc = 0.7071067811865476f * LOG2E;

    // ---- self-attention ----
    {
        float q0 = h0*sa_w_in[0] + h1*sa_w_in[1] + sa_b_in[0];
        float q1 = h0*sa_w_in[2] + h1*sa_w_in[3] + sa_b_in[1];
        float qe0 = q0 * sc, qe1 = q1 * sc;
        const float4* __restrict__ kvp = ws_sa + b * NTOK;   // uniform base
        float l = 0.f, a0 = 0.f, a1 = 0.f;
        #pragma unroll 8
        for (int k = 0; k < NTOK; ++k) {                     // uniform index
            float4 kv = kvp[k];                              // -> s_load
            float p = exp2f(qe0 * kv.x + qe1 * kv.y);
            l  += p;
            a0 += p * kv.z;
            a1 += p * kv.w;
        }
        float rl = 1.0f / l;
        a0 *= rl; a1 *= rl;
        h0 += a0*sa_w_out[0] + a1*sa_w_out[1] + sa_b_out[0];
        h1 += a0*sa_w_out[2] + a1*sa_w_out[3] + sa_b_out[1];
    }

    // ---- LN2 ----
    {
        float diff = 0.5f * (h0 - h1);
        float n = diff * rsqrtf(diff * diff + LN_EPS);
        h0 =  n * ln2_g[0] + ln2_b[0];
        h1 = -n * ln2_g[1] + ln2_b[1];
    }

    // ---- cross-attention ----
    {
        float q0 = h0*ca_w_in[0] + h1*ca_w_in[1] + ca_b_in[0];
        float q1 = h0*ca_w_in[2] + h1*ca_w_in[3] + ca_b_in[1];
        float qe0 = q0 * sc, qe1 = q1 * sc;
        const float4* __restrict__ kvp = ws_ca + b * NTOK;
        float l = 0.f, a0 = 0.f, a1 = 0.f;
        #pragma unroll 8
        for (int k = 0; k < NTOK; ++k) {
            float4 kv = kvp[k];
            float p = exp2f(qe0 * kv.x + qe1 * kv.y);
            l  += p;
            a0 += p * kv.z;
            a1 += p * kv.w;
        }
        float rl = 1.0f / l;
        a0 *= rl; a1 *= rl;
        h0 += a0*ca_w_out[0] + a1*ca_w_out[1] + ca_b_out[0];
        h1 += a0*ca_w_out[2] + a1*ca_w_out[3] + ca_b_out[1];
    }

    // ---- LN3 ----
    {
        float diff = 0.5f * (h0 - h1);
        float n = diff * rsqrtf(diff * diff + LN_EPS);
        h0 =  n * ln3_g[0] + ln3_b[0];
        h1 = -n * ln3_g[1] + ln3_b[1];
    }

    // ---- FFN: Linear(2,10) -> LN(10) -> ReLU -> Linear(10,2), residual ----
    {
        float ff[10];
        #pragma unroll
        for (int i = 0; i < 10; ++i)
            ff[i] = h0*f_w1[2*i] + h1*f_w1[2*i+1] + f_b1[i];
        float mu = 0.f;
        #pragma unroll
        for (int i = 0; i < 10; ++i) mu += ff[i];
        mu *= 0.1f;
        float var = 0.f;
        #pragma unroll
        for (int i = 0; i < 10; ++i) { float d = ff[i] - mu; var += d * d; }
        var *= 0.1f;
        float r = rsqrtf(var + LN_EPS);
        float o0 = 0.f, o1 = 0.f;
        #pragma unroll
        for (int i = 0; i < 10; ++i) {
            float n = (ff[i] - mu) * r * f_ln_g[i] + f_ln_b[i];
            n = fmaxf(n, 0.f);
            o0 += n * f_w2[i];
            o1 += n * f_w2[10 + i];
        }
        h0 += o0 + f_b2[0];
        h1 += o1 + f_b2[1];
    }

    ((float2*)out)[b * NTOK + t] = make_float2(h0, h1);
}

extern "C" void kernel_launch(void* const* d_in, const int* in_sizes, int n_in,
                              void* d_out, int out_size, void* d_ws, size_t ws_size,
                              hipStream_t stream) {
    const float* x        = (const float*)d_in[0];
    const float* m        = (const float*)d_in[1];
    const float* sa_w_in  = (const float*)d_in[2];
    const float* sa_b_in  = (const float*)d_in[3];
    const float* sa_w_out = (const float*)d_in[4];
    const float* sa_b_out = (const float*)d_in[5];
    const float* ca_w_in  = (const float*)d_in[6];
    const float* ca_b_in  = (const float*)d_in[7];
    const float* ca_w_out = (const float*)d_in[8];
    const float* ca_b_out = (const float*)d_in[9];
    const float* ln1_g    = (const float*)d_in[10];
    const float* ln1_b    = (const float*)d_in[11];
    const float* ln2_g    = (const float*)d_in[12];
    const float* ln2_b    = (const float*)d_in[13];
    const float* ln3_g    = (const float*)d_in[14];
    const float* ln3_b    = (const float*)d_in[15];
    const float* f_w1     = (const float*)d_in[16];
    const float* f_b1     = (const float*)d_in[17];
    const float* f_ln_g   = (const float*)d_in[18];
    const float* f_ln_b   = (const float*)d_in[19];
    const float* f_w2     = (const float*)d_in[20];
    const float* f_b2     = (const float*)d_in[21];

    const int ntok_total = in_sizes[0] / 2;          // 1024*256
    const int nbatch = ntok_total / NTOK;            // 1024

    float4* ws_sa = (float4*)d_ws;                   // ntok_total float4 = 4 MB
    float4* ws_ca = ws_sa + ntok_total;              // + 4 MB

    kv_producer_kernel<<<ntok_total / 256, 256, 0, stream>>>(
        x, m, sa_w_in, sa_b_in, ca_w_in, ca_b_in, ln1_g, ln1_b, ws_sa, ws_ca);

    att_decoder_kernel<<<nbatch, NTOK, 0, stream>>>(
        x, ws_sa, ws_ca,
        sa_w_in, sa_b_in, sa_w_out, sa_b_out,
        ca_w_in, ca_b_in, ca_w_out, ca_b_out,
        ln1_g, ln1_b, ln2_g, ln2_b, ln3_g, ln3_b,
        f_w1, f_b1, f_ln_g, f_ln_b, f_w2, f_b2,
        (float*)d_out);
}

// Round 3
// 123.965 us; speedup vs baseline: 1.2403x; 1.2403x over previous
//
#include <hip/hip_runtime.h>

#define NTOK 256
#define LOG2E 1.44269504088896340736f
#define LN_EPS 1e-5f

// One block per batch row. 512 threads: thread = (token t, k-half kh).
// Each (t,kh) accumulates softmax partials over 128 keys; halves combine
// through LDS (sums are linear - no max pass needed since exp2 args are
// bounded |arg|<~70, verified absmax==0 in round 1).
__global__ __launch_bounds__(512, 8)
void att_decoder_kernel(
    const float* __restrict__ x, const float* __restrict__ m,
    const float* __restrict__ sa_w_in, const float* __restrict__ sa_b_in,
    const float* __restrict__ sa_w_out, const float* __restrict__ sa_b_out,
    const float* __restrict__ ca_w_in, const float* __restrict__ ca_b_in,
    const float* __restrict__ ca_w_out, const float* __restrict__ ca_b_out,
    const float* __restrict__ ln1_g, const float* __restrict__ ln1_b,
    const float* __restrict__ ln2_g, const float* __restrict__ ln2_b,
    const float* __restrict__ ln3_g, const float* __restrict__ ln3_b,
    const float* __restrict__ f_w1, const float* __restrict__ f_b1,
    const float* __restrict__ f_ln_g, const float* __restrict__ f_ln_b,
    const float* __restrict__ f_w2, const float* __restrict__ f_b2,
    float* __restrict__ out)
{
    const int b   = blockIdx.x;
    const int tid = threadIdx.x;
    const int t   = tid & (NTOK - 1);
    const int kh  = tid >> 8;              // 0/1, wave-uniform (waves 0-3 vs 4-7)

    __shared__ float4 kv_s[NTOK];          // (k0,k1,v0,v1), 4 KB
    __shared__ float4 part_s[512];         // split-k partials, 8 KB

    float2 hv = ((const float2*)x)[b * NTOK + t];
    float h0 = hv.x, h1 = hv.y;

    // ---- LN1 (d=2 closed form) ----
    {
        float diff = 0.5f * (h0 - h1);
        float n = diff * rsqrtf(diff * diff + LN_EPS);
        h0 =  n * ln1_g[0] + ln1_b[0];
        h1 = -n * ln1_g[1] + ln1_b[1];
    }

    const float sc = 0.7071067811865476f * LOG2E;

    // ---- self-attention ----
    {
        float q0 = h0*sa_w_in[0] + h1*sa_w_in[1] + sa_b_in[0];
        float q1 = h0*sa_w_in[2] + h1*sa_w_in[3] + sa_b_in[1];
        float qe0 = q0 * sc, qe1 = q1 * sc;
        if (kh == 0) {                      // half 0 stages KV (from LN1(x))
            float4 kv;
            kv.x = h0*sa_w_in[4]  + h1*sa_w_in[5]  + sa_b_in[2];
            kv.y = h0*sa_w_in[6]  + h1*sa_w_in[7]  + sa_b_in[3];
            kv.z = h0*sa_w_in[8]  + h1*sa_w_in[9]  + sa_b_in[4];
            kv.w = h0*sa_w_in[10] + h1*sa_w_in[11] + sa_b_in[5];
            kv_s[t] = kv;
        }
        __syncthreads();
        const int kbase = kh * (NTOK / 2);
        float l = 0.f, a0 = 0.f, a1 = 0.f;
        #pragma unroll 8
        for (int k = 0; k < NTOK / 2; ++k) {
            float4 kv = kv_s[kbase + k];            // broadcast ds_read_b128
            float s = qe0 * kv.x + qe1 * kv.y;
            float p = __builtin_amdgcn_exp2f(s);    // raw v_exp_f32
            l  += p;
            a0 += p * kv.z;
            a1 += p * kv.w;
        }
        part_s[tid] = make_float4(l, a0, a1, 0.f);
        __syncthreads();
        float4 o = part_s[tid ^ 256];
        l += o.x; a0 += o.y; a1 += o.z;
        float rl = 1.0f / l;
        a0 *= rl; a1 *= rl;
        h0 += a0*sa_w_out[0] + a1*sa_w_out[1] + sa_b_out[0];
        h1 += a0*sa_w_out[2] + a1*sa_w_out[3] + sa_b_out[1];
    }

    // ---- LN2 ----
    {
        float diff = 0.5f * (h0 - h1);
        float n = diff * rsqrtf(diff * diff + LN_EPS);
        h0 =  n * ln2_g[0] + ln2_b[0];
        h1 = -n * ln2_g[1] + ln2_b[1];
    }

    // ---- cross-attention (KV from raw m) ----
    {
        float q0 = h0*ca_w_in[0] + h1*ca_w_in[1] + ca_b_in[0];
        float q1 = h0*ca_w_in[2] + h1*ca_w_in[3] + ca_b_in[1];
        float qe0 = q0 * sc, qe1 = q1 * sc;
        if (kh == 0) {
            float2 mv = ((const float2*)m)[b * NTOK + t];
            float4 kv;
            kv.x = mv.x*ca_w_in[4]  + mv.y*ca_w_in[5]  + ca_b_in[2];
            kv.y = mv.x*ca_w_in[6]  + mv.y*ca_w_in[7]  + ca_b_in[3];
            kv.z = mv.x*ca_w_in[8]  + mv.y*ca_w_in[9]  + ca_b_in[4];
            kv.w = mv.x*ca_w_in[10] + mv.y*ca_w_in[11] + ca_b_in[5];
            kv_s[t] = kv;                   // safe: all SA reads precede prev barrier
        }
        __syncthreads();
        const int kbase = kh * (NTOK / 2);
        float l = 0.f, a0 = 0.f, a1 = 0.f;
        #pragma unroll 8
        for (int k = 0; k < NTOK / 2; ++k) {
            float4 kv = kv_s[kbase + k];
            float s = qe0 * kv.x + qe1 * kv.y;
            float p = __builtin_amdgcn_exp2f(s);
            l  += p;
            a0 += p * kv.z;
            a1 += p * kv.w;
        }
        part_s[tid] = make_float4(l, a0, a1, 0.f);
        __syncthreads();
        float4 o = part_s[tid ^ 256];
        l += o.x; a0 += o.y; a1 += o.z;
        float rl = 1.0f / l;
        a0 *= rl; a1 *= rl;
        h0 += a0*ca_w_out[0] + a1*ca_w_out[1] + ca_b_out[0];
        h1 += a0*ca_w_out[2] + a1*ca_w_out[3] + ca_b_out[1];
    }

    // half-1 waves are done (no more barriers); half-0 finishes the token.
    if (kh != 0) return;

    // ---- LN3 ----
    {
        float diff = 0.5f * (h0 - h1);
        float n = diff * rsqrtf(diff * diff + LN_EPS);
        h0 =  n * ln3_g[0] + ln3_b[0];
        h1 = -n * ln3_g[1] + ln3_b[1];
    }

    // ---- FFN: Linear(2,10) -> LN(10) -> ReLU -> Linear(10,2), residual ----
    {
        float ff[10];
        #pragma unroll
        for (int i = 0; i < 10; ++i)
            ff[i] = h0*f_w1[2*i] + h1*f_w1[2*i+1] + f_b1[i];
        float mu = 0.f;
        #pragma unroll
        for (int i = 0; i < 10; ++i) mu += ff[i];
        mu *= 0.1f;
        float var = 0.f;
        #pragma unroll
        for (int i = 0; i < 10; ++i) { float d = ff[i] - mu; var += d * d; }
        var *= 0.1f;
        float r = rsqrtf(var + LN_EPS);
        float o0 = 0.f, o1 = 0.f;
        #pragma unroll
        for (int i = 0; i < 10; ++i) {
            float n = (ff[i] - mu) * r * f_ln_g[i] + f_ln_b[i];
            n = fmaxf(n, 0.f);
            o0 += n * f_w2[i];              // f_w2 is [2,10] row-major
            o1 += n * f_w2[10 + i];
        }
        h0 += o0 + f_b2[0];
        h1 += o1 + f_b2[1];
    }

    ((float2*)out)[b * NTOK + t] = make_float2(h0, h1);
}

extern "C" void kernel_launch(void* const* d_in, const int* in_sizes, int n_in,
                              void* d_out, int out_size, void* d_ws, size_t ws_size,
                              hipStream_t stream) {
    const float* x        = (const float*)d_in[0];
    const float* m        = (const float*)d_in[1];
    const float* sa_w_in  = (const float*)d_in[2];
    const float* sa_b_in  = (const float*)d_in[3];
    const float* sa_w_out = (const float*)d_in[4];
    const float* sa_b_out = (const float*)d_in[5];
    const float* ca_w_in  = (const float*)d_in[6];
    const float* ca_b_in  = (const float*)d_in[7];
    const float* ca_w_out = (const float*)d_in[8];
    const float* ca_b_out = (const float*)d_in[9];
    const float* ln1_g    = (const float*)d_in[10];
    const float* ln1_b    = (const float*)d_in[11];
    const float* ln2_g    = (const float*)d_in[12];
    const float* ln2_b    = (const float*)d_in[13];
    const float* ln3_g    = (const float*)d_in[14];
    const float* ln3_b    = (const float*)d_in[15];
    const float* f_w1     = (const float*)d_in[16];
    const float* f_b1     = (const float*)d_in[17];
    const float* f_ln_g   = (const float*)d_in[18];
    const float* f_ln_b   = (const float*)d_in[19];
    const float* f_w2     = (const float*)d_in[20];
    const float* f_b2     = (const float*)d_in[21];

    const int nbatch = in_sizes[0] / (NTOK * 2);   // 1024
    att_decoder_kernel<<<nbatch, 512, 0, stream>>>(
        x, m, sa_w_in, sa_b_in, sa_w_out, sa_b_out,
        ca_w_in, ca_b_in, ca_w_out, ca_b_out,
        ln1_g, ln1_b, ln2_g, ln2_b, ln3_g, ln3_b,
        f_w1, f_b1, f_ln_g, f_ln_b, f_w2, f_b2,
        (float*)d_out);
}